// Round 2
// baseline (321.848 us; speedup 1.0000x reference)
//
#include <hip/hip_runtime.h>

#define T_ 32
#define S_ 4096
#define F_ 256
#define A_ 64

typedef __attribute__((ext_vector_type(8))) short s8v;   // 8 x bf16 (MFMA A/B frag)
typedef __attribute__((ext_vector_type(4))) float f4v;   // 4 x f32  (MFMA C/D frag)
typedef __attribute__((ext_vector_type(4))) short s4v;   // 8-byte packed store

#define MFMA(a, b, c) __builtin_amdgcn_mfma_f32_16x16x32_bf16((a), (b), (c), 0, 0, 0)

__device__ __forceinline__ unsigned short f2bf(float f) {
    unsigned int u = __builtin_bit_cast(unsigned int, f);
    u += 0x7FFFu + ((u >> 16) & 1u);   // round-to-nearest-even
    return (unsigned short)(u >> 16);
}

// ---- pre-pass: convert Wa[64x256], Wb[64x256], Wg[256x256] f32 -> bf16 in d_ws ----
// ws layout (shorts): WaB @0, WbB @16384, WgB @32768   (total 98304 shorts = 192 KB)
__global__ void convert_weights(const float* __restrict__ Wa,
                                const float* __restrict__ Wb,
                                const float* __restrict__ Wg,
                                unsigned short* __restrict__ wsB)
{
    int base = (blockIdx.x * 256 + threadIdx.x) * 4;     // 24576 threads x 4 elems
    const float* src;
    if (base < 16384)      src = Wa + base;
    else if (base < 32768) src = Wb + (base - 16384);
    else                   src = Wg + (base - 32768);
    float4 v = *(const float4*)src;
    s4v p;
    p[0] = (short)f2bf(v.x); p[1] = (short)f2bf(v.y);
    p[2] = (short)f2bf(v.z); p[3] = (short)f2bf(v.w);
    *(s4v*)(wsB + base) = p;
}

// LDS byte offsets
#define XS_OFF 0          // X_s   [32][256] bf16, rows 512 B, 16B-chunk swizzled
#define FT_OFF 16384      // featsT[256][32] bf16, rows 64 B, chunk-swizzled
#define TH_OFF 32768      // theta [32][64]  bf16, rows 128 B, chunk-swizzled
#define PH_OFF 36864      // phi   [32][64]  bf16
#define AT_OFF 40960      // attn  [32][32]  bf16, rows 64 B
#define LDS_BYTES 43008

__global__ __launch_bounds__(256, 2) void fused_temporal(
    const float* __restrict__ X,
    const unsigned short* __restrict__ wsB,
    const float* __restrict__ ba, const float* __restrict__ bb,
    const float* __restrict__ bg,
    float* __restrict__ out)
{
    __shared__ alignas(16) unsigned char smem[LDS_BYTES];
    const int tid  = threadIdx.x;
    const int wave = tid >> 6;
    const int lane = tid & 63;
    const int quad = lane >> 4;
    const int l15  = lane & 15;
    const int s    = blockIdx.x;

    const unsigned short* WaB = wsB;
    const unsigned short* WbB = wsB + 16384;
    const unsigned short* WgB = wsB + 32768;

    // ---- Phase 0: stage X_s [32 rows x 256 f32], convert to bf16, XOR-swizzled 16B chunks ----
    #pragma unroll
    for (int i = 0; i < 4; ++i) {
        int linear = i * 256 + tid;            // 0..1023 bf16 chunks of 16 B (8 elems)
        int t = linear >> 5;                   // row 0..31
        int c = linear & 31;                   // 8-elem chunk in row
        const float* xp = X + ((size_t)(t * S_ + s)) * F_ + c * 8;
        float4 v0 = *(const float4*)(xp);
        float4 v1 = *(const float4*)(xp + 4);
        s8v p;
        p[0] = (short)f2bf(v0.x); p[1] = (short)f2bf(v0.y);
        p[2] = (short)f2bf(v0.z); p[3] = (short)f2bf(v0.w);
        p[4] = (short)f2bf(v1.x); p[5] = (short)f2bf(v1.y);
        p[6] = (short)f2bf(v1.z); p[7] = (short)f2bf(v1.w);
        *(s8v*)(&smem[XS_OFF + t * 512 + (((c + t) & 31) << 4)]) = p;
    }
    __syncthreads();

    // ---- A-fragments of X_s: A[m=lane&15][k=quad*8+j], 2 m-tiles x 8 k-steps ----
    s8v afrag[2][8];
    #pragma unroll
    for (int mt = 0; mt < 2; ++mt) {
        int t = l15 + 16 * mt;
        #pragma unroll
        for (int ks = 0; ks < 8; ++ks) {
            int chunk = 4 * ks + quad;
            afrag[mt][ks] = *(const s8v*)(&smem[XS_OFF + t * 512 + (((chunk + t) & 31) << 4)]);
        }
    }

    // ---- Phase 1a: theta & phi, wave w owns cols [16w,16w+16) ----
    {
        int n0 = 16 * wave;
        f4v ta0 = {0.f,0.f,0.f,0.f}, ta1 = {0.f,0.f,0.f,0.f};
        f4v pa0 = {0.f,0.f,0.f,0.f}, pa1 = {0.f,0.f,0.f,0.f};
        const unsigned short* wa_row = WaB + (size_t)(n0 + l15) * F_ + quad * 8;
        const unsigned short* wb_row = WbB + (size_t)(n0 + l15) * F_ + quad * 8;
        #pragma unroll
        for (int ks = 0; ks < 8; ++ks) {
            s8v bfa = *(const s8v*)(wa_row + ks * 32);
            s8v bfb = *(const s8v*)(wb_row + ks * 32);
            ta0 = MFMA(afrag[0][ks], bfa, ta0);
            ta1 = MFMA(afrag[1][ks], bfa, ta1);
            pa0 = MFMA(afrag[0][ks], bfb, pa0);
            pa1 = MFMA(afrag[1][ks], bfb, pa1);
        }
        float biasa = ba[n0 + l15];
        float biasb = bb[n0 + l15];
        int a_col = n0 + l15;
        int chunk = a_col >> 3;
        int sub   = (a_col & 7) * 2;
        #pragma unroll
        for (int mt = 0; mt < 2; ++mt) {
            f4v va = mt ? ta1 : ta0;
            f4v vb = mt ? pa1 : pa0;
            #pragma unroll
            for (int r = 0; r < 4; ++r) {
                int t  = quad * 4 + r + 16 * mt;
                int sw = ((chunk + t) & 7) << 4;
                *(unsigned short*)(&smem[TH_OFF + t * 128 + sw + sub]) = f2bf(va[r] + biasa);
                *(unsigned short*)(&smem[PH_OFF + t * 128 + sw + sub]) = f2bf(vb[r] + biasb);
            }
        }
    }

    // ---- Phase 1b: feats, wave w owns cols [64w,64w+64); stored transposed [f][u] ----
    #pragma unroll
    for (int g = 0; g < 4; ++g) {
        int n0 = 64 * wave + 16 * g;
        f4v fa0 = {0.f,0.f,0.f,0.f}, fa1 = {0.f,0.f,0.f,0.f};
        const unsigned short* wg_row = WgB + (size_t)(n0 + l15) * F_ + quad * 8;
        #pragma unroll
        for (int ks = 0; ks < 8; ++ks) {
            s8v bf = *(const s8v*)(wg_row + ks * 32);
            fa0 = MFMA(afrag[0][ks], bf, fa0);
            fa1 = MFMA(afrag[1][ks], bf, fa1);
        }
        float biasg = bg[n0 + l15];
        int f = n0 + l15;
        #pragma unroll
        for (int mt = 0; mt < 2; ++mt) {
            f4v v = mt ? fa1 : fa0;
            int u0 = quad * 4 + 16 * mt;            // 4 consecutive u per lane
            s4v pk;
            #pragma unroll
            for (int r = 0; r < 4; ++r) pk[r] = (short)f2bf(v[r] + biasg);
            int addr = FT_OFF + f * 64 + ((((u0 >> 3) + f) & 3) << 4) + (u0 & 7) * 2;
            *(s4v*)(&smem[addr]) = pk;              // ds_write_b64
        }
    }
    __syncthreads();

    // ---- Phase 2: attn[t][u] = sum_a theta[t][a] * phi[u][a]; wave w -> tile (w>>1, w&1) ----
    {
        int mt = wave >> 1, nt = wave & 1;
        int t = l15 + 16 * mt;
        int u = l15 + 16 * nt;
        f4v acc = {0.f,0.f,0.f,0.f};
        #pragma unroll
        for (int ks = 0; ks < 2; ++ks) {
            int chunk = 4 * ks + quad;
            s8v av = *(const s8v*)(&smem[TH_OFF + t * 128 + (((chunk + t) & 7) << 4)]);
            s8v bv = *(const s8v*)(&smem[PH_OFF + u * 128 + (((chunk + u) & 7) << 4)]);
            acc = MFMA(av, bv, acc);
        }
        int chunk = u >> 3;
        int sub   = (u & 7) * 2;
        #pragma unroll
        for (int r = 0; r < 4; ++r) {
            int tt = quad * 4 + r + 16 * mt;
            *(unsigned short*)(&smem[AT_OFF + tt * 64 + (((chunk + tt) & 3) << 4) + sub]) = f2bf(acc[r]);
        }
    }
    __syncthreads();

    // ---- Phase 3: out[t][f] = sum_u attn[t][u] * feats[u][f]; K=32 in one MFMA ----
    {
        s8v aa[2];
        #pragma unroll
        for (int mt = 0; mt < 2; ++mt) {
            int t = l15 + 16 * mt;
            aa[mt] = *(const s8v*)(&smem[AT_OFF + t * 64 + (((quad + t) & 3) << 4)]);
        }
        #pragma unroll
        for (int g = 0; g < 4; ++g) {
            int n0 = 64 * wave + 16 * g;
            int f  = n0 + l15;
            s8v bv = *(const s8v*)(&smem[FT_OFF + f * 64 + (((quad + f) & 3) << 4)]);
            #pragma unroll
            for (int mt = 0; mt < 2; ++mt) {
                f4v acc = {0.f,0.f,0.f,0.f};
                acc = MFMA(aa[mt], bv, acc);
                #pragma unroll
                for (int r = 0; r < 4; ++r) {
                    int t = quad * 4 + r + 16 * mt;
                    out[((size_t)(t * S_ + s)) * F_ + f] = acc[r];
                }
            }
        }
    }
}

extern "C" void kernel_launch(void* const* d_in, const int* in_sizes, int n_in,
                              void* d_out, int out_size, void* d_ws, size_t ws_size,
                              hipStream_t stream) {
    (void)in_sizes; (void)n_in; (void)ws_size; (void)out_size;
    const float* X  = (const float*)d_in[0];   // batch_data [T*S, F] f32
    // d_in[1] = xywh (dead path)
    const float* Wa = (const float*)d_in[2];
    const float* ba = (const float*)d_in[3];
    const float* Wb = (const float*)d_in[4];
    const float* bb = (const float*)d_in[5];
    const float* Wg = (const float*)d_in[6];
    const float* bg = (const float*)d_in[7];
    // d_in[8] = Wh, d_in[9] = bh (dead path)
    float* out = (float*)d_out;
    unsigned short* wsB = (unsigned short*)d_ws;   // 192 KB bf16 weights

    convert_weights<<<dim3(96), dim3(256), 0, stream>>>(Wa, Wb, Wg, wsB);
    fused_temporal<<<dim3(S_), dim3(256), 0, stream>>>(X, wsB, ba, bb, bg, out);
}